// Round 3
// baseline (11587.727 us; speedup 1.0000x reference)
//
#include <hip/hip_runtime.h>
#include <stdint.h>

#define BATCHES 32
#define NPT     100000
#define NSAMP   1024
#define GPB     16         // blocks (groups) per batch
#define TPB     512
#define PPB     6250       // points per block (16*6250 = 100000 exactly)
#define PPT     13         // ceil(6250/512); k=0..11 full, k=12 only tid<106
#define TAILT   106        // 6250 - 12*512
#define NW      (TPB/64)   // 8 waves per block

typedef unsigned long long u64;
typedef unsigned int u32;

// One 32-byte record per (parity, batch, group):
//   w0 = f64 distance bits (monotone for >=0)
//   w1 = (y_bits<<32) | x_bits
//   w2 = (idx<<32)    | z_bits
//   w3 = tag (= it+1), release-published
struct alignas(32) Rec { u64 key; u64 xy; u64 zi; u64 tag; };
#define WS_BYTES (2 * BATCHES * GPB * (int)sizeof(Rec))   // 32 KB

__device__ __forceinline__ void red_step(u64& key, u32& idx, float& x, float& y, float& z, int off) {
    u64   ok = __shfl_xor(key, off, 64);
    u32   oi = __shfl_xor(idx, off, 64);
    float ox = __shfl_xor(x, off, 64);
    float oy = __shfl_xor(y, off, 64);
    float oz = __shfl_xor(z, off, 64);
    if (ok > key || (ok == key && oi < idx)) { key = ok; idx = oi; x = ox; y = oy; z = oz; }
}

__launch_bounds__(TPB, 4)
__global__ void fps_kernel(const float* __restrict__ coord,
                           const int* __restrict__ seed_raw,
                           float* __restrict__ out,
                           Rec* __restrict__ rec)
{
    const int tid  = threadIdx.x;
    const int lane = tid & 63;
    const int wid  = tid >> 6;
    // Swizzle: all 16 groups of a batch share blockIdx%8 -> same XCD under
    // round-robin dispatch (locality heuristic only; correctness-independent).
    const int b    = (int)blockIdx.x & 31;
    const int g    = (int)blockIdx.x >> 5;
    const int base = g * PPB;
    const float* cb = coord + (size_t)b * (NPT * 3);

    // f64 running min-distance lives in LDS (52 KB) -> no register spills.
    __shared__ double sd[PPT * TPB];
    __shared__ u64   wkey[NW];
    __shared__ u32   widx[NW];
    __shared__ float wx[NW], wy[NW], wz[NW];
    __shared__ u32   s_win;
    __shared__ float s_cx, s_cy, s_cz;

    // Seed index (robust to int32 or int64 materialization of farthest_init).
    int odd = 0;
    #pragma unroll
    for (int i = 1; i < 32; i += 2) odd |= seed_raw[i];
    int cur = (odd == 0) ? seed_raw[2 * b] : seed_raw[b];

    float cx = cb[(size_t)cur * 3 + 0];
    float cy = cb[(size_t)cur * 3 + 1];
    float cz = cb[(size_t)cur * 3 + 2];

    // Coords in f32 registers (39 VGPRs persistent).
    float px[PPT], py[PPT], pz[PPT];
    #pragma unroll
    for (int k = 0; k < PPT; ++k) {
        bool v = (k < 12) || (tid < TAILT);
        int gi = base + (v ? (k * TPB + tid) : 0);
        px[k] = v ? cb[(size_t)gi * 3 + 0] : 0.f;
        py[k] = v ? cb[(size_t)gi * 3 + 1] : 0.f;
        pz[k] = v ? cb[(size_t)gi * 3 + 2] : 0.f;
        sd[k * TPB + tid] = v ? 1.0e10 : 0.0;
    }
    __syncthreads();

    float* cent_out = out;                       // (B, 1024) as float
    float* samp_out = out + BATCHES * NSAMP;     // (B, 1024, 3)

    for (int it = 0; it < NSAMP; ++it) {
        if (g == 0 && tid == 0) {
            cent_out[b * NSAMP + it] = (float)cur;
            size_t so = ((size_t)b * NSAMP + it) * 3;
            samp_out[so + 0] = cx; samp_out[so + 1] = cy; samp_out[so + 2] = cz;
        }

        const double cxd = (double)cx, cyd = (double)cy, czd = (double)cz;

        // f64 update + per-thread argmax. Explicit _rn ops forbid FMA
        // contraction; sum order ((dx^2+dy^2)+dz^2) matches np.sum(axis=-1).
        double bd = -1.0; u32 bi = 0; float bx = 0.f, by = 0.f, bz = 0.f;
        #pragma unroll
        for (int k = 0; k < 12; ++k) {
            double dx = __dsub_rn((double)px[k], cxd);
            double dy = __dsub_rn((double)py[k], cyd);
            double dz = __dsub_rn((double)pz[k], czd);
            double d2 = __dadd_rn(__dadd_rn(__dmul_rn(dx, dx), __dmul_rn(dy, dy)),
                                  __dmul_rn(dz, dz));
            double nd = fmin(sd[k * TPB + tid], d2);
            sd[k * TPB + tid] = nd;
            bool gt = nd > bd;       // strict > keeps smallest k (== smallest idx)
            bd = gt ? nd : bd;
            bi = gt ? (u32)(base + k * TPB + tid) : bi;
            bx = gt ? px[k] : bx;
            by = gt ? py[k] : by;
            bz = gt ? pz[k] : bz;
        }
        if (tid < TAILT) {
            const int k = 12;
            double dx = __dsub_rn((double)px[k], cxd);
            double dy = __dsub_rn((double)py[k], cyd);
            double dz = __dsub_rn((double)pz[k], czd);
            double d2 = __dadd_rn(__dadd_rn(__dmul_rn(dx, dx), __dmul_rn(dy, dy)),
                                  __dmul_rn(dz, dz));
            double nd = fmin(sd[k * TPB + tid], d2);
            sd[k * TPB + tid] = nd;
            bool gt = nd > bd;
            bd = gt ? nd : bd;
            bi = gt ? (u32)(base + k * TPB + tid) : bi;
            bx = gt ? px[k] : bx;
            by = gt ? py[k] : by;
            bz = gt ? pz[k] : bz;
        }
        u64 key = (u64)__double_as_longlong(bd);   // bd >= 0 -> monotone bits

        // Wave reduction.
        red_step(key, bi, bx, by, bz, 32); red_step(key, bi, bx, by, bz, 16);
        red_step(key, bi, bx, by, bz, 8);  red_step(key, bi, bx, by, bz, 4);
        red_step(key, bi, bx, by, bz, 2);  red_step(key, bi, bx, by, bz, 1);
        if (lane == 0) { wkey[wid] = key; widx[wid] = bi; wx[wid] = bx; wy[wid] = by; wz[wid] = bz; }
        __syncthreads();

        if (wid == 0) {
            // Block-level reduce over 8 wave results (lanes 0..7).
            u64   k2 = (lane < NW) ? wkey[lane] : 0ull;
            u32   i2 = (lane < NW) ? widx[lane] : 0xFFFFFFFFu;
            float x2 = (lane < NW) ? wx[lane] : 0.f;
            float y2 = (lane < NW) ? wy[lane] : 0.f;
            float z2 = (lane < NW) ? wz[lane] : 0.f;
            red_step(k2, i2, x2, y2, z2, 4); red_step(k2, i2, x2, y2, z2, 2); red_step(k2, i2, x2, y2, z2, 1);

            const int par = it & 1;   // parity double-buffer (reuse at distance 2
                                      // is provably consumed — see protocol note)
            Rec* r = rec + ((par * BATCHES + b) * GPB + g);
            if (lane == 0) {
                __hip_atomic_store(&r->key, k2, __ATOMIC_RELAXED, __HIP_MEMORY_SCOPE_AGENT);
                u64 xy = ((u64)__float_as_uint(y2) << 32) | __float_as_uint(x2);
                __hip_atomic_store(&r->xy, xy, __ATOMIC_RELAXED, __HIP_MEMORY_SCOPE_AGENT);
                u64 zi = ((u64)i2 << 32) | __float_as_uint(z2);
                __hip_atomic_store(&r->zi, zi, __ATOMIC_RELAXED, __HIP_MEMORY_SCOPE_AGENT);
                // Release: orders the three data stores before the tag.
                __hip_atomic_store(&r->tag, (u64)(it + 1), __ATOMIC_RELEASE, __HIP_MEMORY_SCOPE_AGENT);
            }
            // Spin on tags with RELAXED loads (no per-load invalidate), then one
            // acquire fence before consuming data.
            const u64 target = (u64)(it + 1);
            Rec* rb = rec + (par * BATCHES + b) * GPB;
            for (;;) {
                u64 t = (lane < GPB)
                    ? __hip_atomic_load(&rb[lane].tag, __ATOMIC_RELAXED, __HIP_MEMORY_SCOPE_AGENT)
                    : target;
                if (__ballot(t >= target) == ~0ull) break;
                __builtin_amdgcn_s_sleep(1);
            }
            __builtin_amdgcn_fence(__ATOMIC_ACQUIRE, "agent");
            u64 k3 = 0ull; u32 i3 = 0xFFFFFFFFu; float x3 = 0.f, y3 = 0.f, z3 = 0.f;
            if (lane < GPB) {
                u64 kk = __hip_atomic_load(&rb[lane].key, __ATOMIC_RELAXED, __HIP_MEMORY_SCOPE_AGENT);
                u64 xy = __hip_atomic_load(&rb[lane].xy,  __ATOMIC_RELAXED, __HIP_MEMORY_SCOPE_AGENT);
                u64 zi = __hip_atomic_load(&rb[lane].zi,  __ATOMIC_RELAXED, __HIP_MEMORY_SCOPE_AGENT);
                k3 = kk;
                x3 = __uint_as_float((u32)xy);
                y3 = __uint_as_float((u32)(xy >> 32));
                z3 = __uint_as_float((u32)zi);
                i3 = (u32)(zi >> 32);
            }
            red_step(k3, i3, x3, y3, z3, 8); red_step(k3, i3, x3, y3, z3, 4);
            red_step(k3, i3, x3, y3, z3, 2); red_step(k3, i3, x3, y3, z3, 1);
            if (lane == 0) { s_win = i3; s_cx = x3; s_cy = y3; s_cz = z3; }
        }
        __syncthreads();
        cur = (int)s_win; cx = s_cx; cy = s_cy; cz = s_cz;
    }
}

extern "C" void kernel_launch(void* const* d_in, const int* in_sizes, int n_in,
                              void* d_out, int out_size, void* d_ws, size_t ws_size,
                              hipStream_t stream)
{
    const float* coord = (const float*)d_in[0];
    const int*   seed  = (const int*)d_in[1];
    float* out = (float*)d_out;
    Rec* rec = (Rec*)d_ws;

    hipMemsetAsync(d_ws, 0, WS_BYTES, stream);
    fps_kernel<<<dim3(BATCHES * GPB), dim3(TPB), 0, stream>>>(coord, seed, out, rec);
}

// Round 4
// 9798.860 us; speedup vs baseline: 1.1826x; 1.1826x over previous
//
#include <hip/hip_runtime.h>
#include <stdint.h>

#define BATCHES 32
#define NPT     100000
#define NSAMP   1024
#define GPB     16         // blocks (groups) per batch
#define TPB     512
#define PPB     6250       // points per block (16*6250 = 100000 exactly)
#define PPT     13         // ceil(6250/512); k=0..11 full, k=12 only tid<106
#define TAILT   106        // 6250 - 12*512
#define NW      (TPB/64)   // 8 waves per block

typedef unsigned long long u64;
typedef unsigned int u32;

// Partial per (parity, batch, group): 32 B.
struct alignas(32) Rec { u64 key; u64 xy; u64 zi; u64 pad; };
// Final per (parity, batch): 64 B (own cache line -> no cross-batch sharing).
//   ti = ((it+1)<<32) | winner_idx   (tag+idx read atomically by pollers)
struct alignas(64) Fin { u64 ti; u64 xy; u64 z; u64 pad[5]; };
// Arrival counter per (parity, batch): 64 B padded. Monotone, never reset.
struct alignas(64) Cnt { u32 c; u32 pad[15]; };

#define REC_BYTES (2 * BATCHES * GPB * (int)sizeof(Rec))   // 32 KB
#define FIN_BYTES (2 * BATCHES * (int)sizeof(Fin))         // 4 KB
#define CNT_BYTES (2 * BATCHES * (int)sizeof(Cnt))         // 4 KB
#define WS_BYTES  (REC_BYTES + FIN_BYTES + CNT_BYTES)

__device__ __forceinline__ void red_step(u64& key, u32& idx, float& x, float& y, float& z, int off) {
    u64   ok = __shfl_xor(key, off, 64);
    u32   oi = __shfl_xor(idx, off, 64);
    float ox = __shfl_xor(x, off, 64);
    float oy = __shfl_xor(y, off, 64);
    float oz = __shfl_xor(z, off, 64);
    if (ok > key || (ok == key && oi < idx)) { key = ok; idx = oi; x = ox; y = oy; z = oz; }
}

__launch_bounds__(TPB, 4)
__global__ void fps_kernel(const float* __restrict__ coord,
                           const int* __restrict__ seed_raw,
                           float* __restrict__ out,
                           Rec* __restrict__ rec,
                           Fin* __restrict__ fin,
                           Cnt* __restrict__ cnt)
{
    const int tid  = threadIdx.x;
    const int lane = tid & 63;
    const int wid  = tid >> 6;
    // Swizzle: all 16 groups of a batch share blockIdx%8 -> same XCD under
    // round-robin dispatch (locality heuristic only).
    const int b    = (int)blockIdx.x & 31;
    const int g    = (int)blockIdx.x >> 5;
    const int base = g * PPB;
    const float* cb = coord + (size_t)b * (NPT * 3);

    // f64 running min-distance in LDS (52 KB) -> no register spills.
    __shared__ double sd[PPT * TPB];
    __shared__ u64   wkey[NW];
    __shared__ u32   widx[NW];
    __shared__ float wx[NW], wy[NW], wz[NW];
    __shared__ u32   s_win;
    __shared__ float s_cx, s_cy, s_cz;

    // Seed index (robust to int32 or int64 materialization of farthest_init).
    int odd = 0;
    #pragma unroll
    for (int i = 1; i < 32; i += 2) odd |= seed_raw[i];
    int cur = (odd == 0) ? seed_raw[2 * b] : seed_raw[b];

    float cx = cb[(size_t)cur * 3 + 0];
    float cy = cb[(size_t)cur * 3 + 1];
    float cz = cb[(size_t)cur * 3 + 2];

    // Coords in f32 registers (39 VGPRs persistent).
    float px[PPT], py[PPT], pz[PPT];
    #pragma unroll
    for (int k = 0; k < PPT; ++k) {
        bool v = (k < 12) || (tid < TAILT);
        int gi = base + (v ? (k * TPB + tid) : 0);
        px[k] = v ? cb[(size_t)gi * 3 + 0] : 0.f;
        py[k] = v ? cb[(size_t)gi * 3 + 1] : 0.f;
        pz[k] = v ? cb[(size_t)gi * 3 + 2] : 0.f;
        sd[k * TPB + tid] = v ? 1.0e10 : 0.0;
    }
    __syncthreads();

    float* cent_out = out;                       // (B, 1024) as float
    float* samp_out = out + BATCHES * NSAMP;     // (B, 1024, 3)

    for (int it = 0; it < NSAMP; ++it) {
        if (g == 0 && tid == 0) {
            cent_out[b * NSAMP + it] = (float)cur;
            size_t so = ((size_t)b * NSAMP + it) * 3;
            samp_out[so + 0] = cx; samp_out[so + 1] = cy; samp_out[so + 2] = cz;
        }

        const double cxd = (double)cx, cyd = (double)cy, czd = (double)cz;

        // f64 update + per-thread argmax. Explicit _rn ops forbid FMA
        // contraction; sum order ((dx^2+dy^2)+dz^2) matches np.sum(axis=-1).
        double bd = -1.0; u32 bi = 0; float bx = 0.f, by = 0.f, bz = 0.f;
        #pragma unroll
        for (int k = 0; k < 12; ++k) {
            double dx = __dsub_rn((double)px[k], cxd);
            double dy = __dsub_rn((double)py[k], cyd);
            double dz = __dsub_rn((double)pz[k], czd);
            double d2 = __dadd_rn(__dadd_rn(__dmul_rn(dx, dx), __dmul_rn(dy, dy)),
                                  __dmul_rn(dz, dz));
            double nd = fmin(sd[k * TPB + tid], d2);
            sd[k * TPB + tid] = nd;
            bool gt = nd > bd;       // strict > keeps smallest k (== smallest idx)
            bd = gt ? nd : bd;
            bi = gt ? (u32)(base + k * TPB + tid) : bi;
            bx = gt ? px[k] : bx;
            by = gt ? py[k] : by;
            bz = gt ? pz[k] : bz;
        }
        if (tid < TAILT) {
            const int k = 12;
            double dx = __dsub_rn((double)px[k], cxd);
            double dy = __dsub_rn((double)py[k], cyd);
            double dz = __dsub_rn((double)pz[k], czd);
            double d2 = __dadd_rn(__dadd_rn(__dmul_rn(dx, dx), __dmul_rn(dy, dy)),
                                  __dmul_rn(dz, dz));
            double nd = fmin(sd[k * TPB + tid], d2);
            sd[k * TPB + tid] = nd;
            bool gt = nd > bd;
            bd = gt ? nd : bd;
            bi = gt ? (u32)(base + k * TPB + tid) : bi;
            bx = gt ? px[k] : bx;
            by = gt ? py[k] : by;
            bz = gt ? pz[k] : bz;
        }
        u64 key = (u64)__double_as_longlong(bd);   // bd >= 0 -> monotone bits

        // Wave reduction (winner replicated to all lanes by the butterfly).
        red_step(key, bi, bx, by, bz, 32); red_step(key, bi, bx, by, bz, 16);
        red_step(key, bi, bx, by, bz, 8);  red_step(key, bi, bx, by, bz, 4);
        red_step(key, bi, bx, by, bz, 2);  red_step(key, bi, bx, by, bz, 1);
        if (lane == 0) { wkey[wid] = key; widx[wid] = bi; wx[wid] = bx; wy[wid] = by; wz[wid] = bz; }
        __syncthreads();

        if (wid == 0) {
            // Block-level reduce over 8 wave results (lanes 0..7).
            u64   k2 = (lane < NW) ? wkey[lane] : 0ull;
            u32   i2 = (lane < NW) ? widx[lane] : 0xFFFFFFFFu;
            float x2 = (lane < NW) ? wx[lane] : 0.f;
            float y2 = (lane < NW) ? wy[lane] : 0.f;
            float z2 = (lane < NW) ? wz[lane] : 0.f;
            red_step(k2, i2, x2, y2, z2, 4); red_step(k2, i2, x2, y2, z2, 2); red_step(k2, i2, x2, y2, z2, 1);

            const int s = it & 1;   // parity double-buffer
            Rec* r = rec + ((s * BATCHES + b) * GPB + g);
            Fin* f = fin + (s * BATCHES + b);
            u32 old = 0;
            if (lane == 0) {
                __hip_atomic_store(&r->key, k2, __ATOMIC_RELAXED, __HIP_MEMORY_SCOPE_AGENT);
                u64 xy = ((u64)__float_as_uint(y2) << 32) | __float_as_uint(x2);
                __hip_atomic_store(&r->xy, xy, __ATOMIC_RELAXED, __HIP_MEMORY_SCOPE_AGENT);
                u64 zi = ((u64)i2 << 32) | __float_as_uint(z2);
                __hip_atomic_store(&r->zi, zi, __ATOMIC_RELAXED, __HIP_MEMORY_SCOPE_AGENT);
                // Release: orders the partial stores before the arrival tick.
                old = __hip_atomic_fetch_add(&cnt[s * BATCHES + b].c, 1u,
                                             __ATOMIC_RELEASE, __HIP_MEMORY_SCOPE_AGENT);
            }
            old = __shfl(old, 0, 64);
            const u32 last = (u32)((it >> 1) + 1) * GPB - 1;   // value last arriver sees

            if (old == last) {
                // LEADER: reduce the 16 partials, publish one final record.
                __builtin_amdgcn_fence(__ATOMIC_ACQUIRE, "agent");
                Rec* rb = rec + (s * BATCHES + b) * GPB;
                u64 k3 = 0ull; u32 i3 = 0xFFFFFFFFu; float x3 = 0.f, y3 = 0.f, z3 = 0.f;
                if (lane < GPB) {
                    u64 kk = __hip_atomic_load(&rb[lane].key, __ATOMIC_RELAXED, __HIP_MEMORY_SCOPE_AGENT);
                    u64 xy = __hip_atomic_load(&rb[lane].xy,  __ATOMIC_RELAXED, __HIP_MEMORY_SCOPE_AGENT);
                    u64 zi = __hip_atomic_load(&rb[lane].zi,  __ATOMIC_RELAXED, __HIP_MEMORY_SCOPE_AGENT);
                    k3 = kk;
                    x3 = __uint_as_float((u32)xy);
                    y3 = __uint_as_float((u32)(xy >> 32));
                    z3 = __uint_as_float((u32)zi);
                    i3 = (u32)(zi >> 32);
                }
                red_step(k3, i3, x3, y3, z3, 8); red_step(k3, i3, x3, y3, z3, 4);
                red_step(k3, i3, x3, y3, z3, 2); red_step(k3, i3, x3, y3, z3, 1);
                if (lane == 0) {
                    u64 xy = ((u64)__float_as_uint(y3) << 32) | __float_as_uint(x3);
                    __hip_atomic_store(&f->xy, xy, __ATOMIC_RELAXED, __HIP_MEMORY_SCOPE_AGENT);
                    __hip_atomic_store(&f->z, (u64)__float_as_uint(z3), __ATOMIC_RELAXED, __HIP_MEMORY_SCOPE_AGENT);
                    u64 ti = ((u64)(u32)(it + 1) << 32) | i3;
                    __hip_atomic_store(&f->ti, ti, __ATOMIC_RELEASE, __HIP_MEMORY_SCOPE_AGENT);
                }
            }

            // Everyone polls ONE address (tag+idx word); all lanes same address
            // -> single coalesced request per poll.
            u64 ti;
            for (;;) {
                ti = __hip_atomic_load(&f->ti, __ATOMIC_RELAXED, __HIP_MEMORY_SCOPE_AGENT);
                if ((u32)(ti >> 32) == (u32)(it + 1)) break;
                __builtin_amdgcn_s_sleep(1);
            }
            __builtin_amdgcn_fence(__ATOMIC_ACQUIRE, "agent");
            u64 xy = __hip_atomic_load(&f->xy, __ATOMIC_RELAXED, __HIP_MEMORY_SCOPE_AGENT);
            u64 zz = __hip_atomic_load(&f->z,  __ATOMIC_RELAXED, __HIP_MEMORY_SCOPE_AGENT);
            if (lane == 0) {
                s_win = (u32)ti;
                s_cx = __uint_as_float((u32)xy);
                s_cy = __uint_as_float((u32)(xy >> 32));
                s_cz = __uint_as_float((u32)zz);
            }
        }
        __syncthreads();
        cur = (int)s_win; cx = s_cx; cy = s_cy; cz = s_cz;
    }
}

extern "C" void kernel_launch(void* const* d_in, const int* in_sizes, int n_in,
                              void* d_out, int out_size, void* d_ws, size_t ws_size,
                              hipStream_t stream)
{
    const float* coord = (const float*)d_in[0];
    const int*   seed  = (const int*)d_in[1];
    float* out = (float*)d_out;
    Rec* rec = (Rec*)d_ws;
    Fin* fin = (Fin*)((char*)d_ws + REC_BYTES);
    Cnt* cnt = (Cnt*)((char*)d_ws + REC_BYTES + FIN_BYTES);

    hipMemsetAsync(d_ws, 0, WS_BYTES, stream);
    fps_kernel<<<dim3(BATCHES * GPB), dim3(TPB), 0, stream>>>(coord, seed, out, rec, fin, cnt);
}

// Round 5
// 6811.068 us; speedup vs baseline: 1.7013x; 1.4387x over previous
//
#include <hip/hip_runtime.h>
#include <stdint.h>

#define BATCHES 32
#define NPT     100000
#define NSAMP   1024
#define GPB     8          // blocks (groups) per batch -> 256 blocks = 1/CU
#define TPB     1024
#define PPB     12500      // points per block (8*12500 = 100000)
#define PPT     13         // k=0..11 full (12288), k=12 only tid<212
#define TAILT   212
#define NW      (TPB/64)   // 16 waves per block

typedef unsigned long long u64;
typedef unsigned int u32;

// Partial record per (slot, batch, group): 3 u64 = 24 B.
//   w0 = f64 distance bits (monotone for >= 0)
//   w1 = (y_bits<<32) | x_bits
//   w2 = (meta<<32)   | z_bits,  meta = (tag<<17) | idx   (tag=it+1 <= 1024)
#define WS_BYTES (2 * BATCHES * GPB * 3 * 8)   // 12 KB

__device__ __forceinline__ void red_step(u64& key, u32& idx, float& x, float& y, float& z, int off) {
    u64   ok = __shfl_xor(key, off, 64);
    u32   oi = __shfl_xor(idx, off, 64);
    float ox = __shfl_xor(x, off, 64);
    float oy = __shfl_xor(y, off, 64);
    float oz = __shfl_xor(z, off, 64);
    if (ok > key || (ok == key && oi < idx)) { key = ok; idx = oi; x = ox; y = oy; z = oz; }
}

__launch_bounds__(TPB)   // plain: VGPR cap 128 (16 waves/CU). No min-waves clamp!
__global__ void fps_kernel(const float* __restrict__ coord,
                           const int* __restrict__ seed_raw,
                           float* __restrict__ out,
                           u64* __restrict__ rec)
{
    const int tid  = threadIdx.x;
    const int lane = tid & 63;
    const int wid  = tid >> 6;
    // All 8 groups of a batch land on XCD b%8 under round-robin dispatch.
    const int b    = (int)blockIdx.x & 31;
    const int g    = (int)blockIdx.x >> 5;
    const int base = g * PPB;
    const float* cb = coord + (size_t)b * (NPT * 3);

    __shared__ u64   wkey[NW];
    __shared__ u32   widx[NW];
    __shared__ float wx[NW], wy[NW], wz[NW];
    __shared__ u32   s_win;
    __shared__ float s_cx, s_cy, s_cz;

    // Seed index (robust to int32 or int64 materialization of farthest_init).
    int odd = 0;
    #pragma unroll
    for (int i = 1; i < 32; i += 2) odd |= seed_raw[i];
    int cur = (odd == 0) ? seed_raw[2 * b] : seed_raw[b];

    float cx = cb[(size_t)cur * 3 + 0];
    float cy = cb[(size_t)cur * 3 + 1];
    float cz = cb[(size_t)cur * 3 + 2];

    // Coords (39 f32) AND running min-distance (13 f64) all in registers.
    float  px[PPT], py[PPT], pz[PPT];
    double d[PPT];
    #pragma unroll
    for (int k = 0; k < PPT; ++k) {
        bool v = (k < 12) || (tid < TAILT);
        int gi = base + (v ? (k * TPB + tid) : 0);
        px[k] = v ? cb[(size_t)gi * 3 + 0] : 0.f;
        py[k] = v ? cb[(size_t)gi * 3 + 1] : 0.f;
        pz[k] = v ? cb[(size_t)gi * 3 + 2] : 0.f;
        d[k]  = v ? 1.0e10 : 0.0;   // fake points can never win argmax
    }

    float* cent_out = out;                       // (B, 1024) as float
    float* samp_out = out + BATCHES * NSAMP;     // (B, 1024, 3)

    for (int it = 0; it < NSAMP; ++it) {
        // Outputs written by the otherwise-idle wave 1 (off the sync path).
        if (g == 0 && wid == 1 && lane == 0) {
            cent_out[b * NSAMP + it] = (float)cur;
            size_t so = ((size_t)b * NSAMP + it) * 3;
            samp_out[so + 0] = cx; samp_out[so + 1] = cy; samp_out[so + 2] = cz;
        }

        const double cxd = (double)cx, cyd = (double)cy, czd = (double)cz;

        // f64 update + per-thread argmax. Explicit _rn ops forbid FMA
        // contraction; sum order ((dx^2+dy^2)+dz^2) matches np.sum(axis=-1).
        double bd = -1.0; u32 bi = 0; float bx = 0.f, by = 0.f, bz = 0.f;
        #pragma unroll
        for (int k = 0; k < PPT; ++k) {
            if (k == 12 && tid >= TAILT) break;
            double dx = __dsub_rn((double)px[k], cxd);
            double dy = __dsub_rn((double)py[k], cyd);
            double dz = __dsub_rn((double)pz[k], czd);
            double d2 = __dadd_rn(__dadd_rn(__dmul_rn(dx, dx), __dmul_rn(dy, dy)),
                                  __dmul_rn(dz, dz));
            double nd = fmin(d[k], d2);
            d[k] = nd;
            bool gt = nd > bd;       // strict > keeps smallest k (== smallest idx)
            bd = gt ? nd : bd;
            bi = gt ? (u32)(base + k * TPB + tid) : bi;
            bx = gt ? px[k] : bx;
            by = gt ? py[k] : by;
            bz = gt ? pz[k] : bz;
        }
        u64 key = (u64)__double_as_longlong(bd);   // bd >= 0 -> monotone bits

        // Wave butterfly reduction.
        red_step(key, bi, bx, by, bz, 32); red_step(key, bi, bx, by, bz, 16);
        red_step(key, bi, bx, by, bz, 8);  red_step(key, bi, bx, by, bz, 4);
        red_step(key, bi, bx, by, bz, 2);  red_step(key, bi, bx, by, bz, 1);
        if (lane == 0) { wkey[wid] = key; widx[wid] = bi; wx[wid] = bx; wy[wid] = by; wz[wid] = bz; }
        __syncthreads();

        if (wid == 0) {
            // Block reduce over 16 wave partials (lanes 0..15).
            u64   k2 = (lane < NW) ? wkey[lane] : 0ull;
            u32   i2 = (lane < NW) ? widx[lane] : 0xFFFFFFFFu;
            float x2 = (lane < NW) ? wx[lane] : 0.f;
            float y2 = (lane < NW) ? wy[lane] : 0.f;
            float z2 = (lane < NW) ? wz[lane] : 0.f;
            red_step(k2, i2, x2, y2, z2, 8); red_step(k2, i2, x2, y2, z2, 4);
            red_step(k2, i2, x2, y2, z2, 2); red_step(k2, i2, x2, y2, z2, 1);

            const int s = it & 1;                       // parity double-buffer
            u64* slot = rec + ((size_t)(s * BATCHES + b) * GPB) * 3;
            const u32 target = (u32)(it + 1);
            if (lane == 0) {
                u64* r = slot + g * 3;
                __hip_atomic_store(&r[0], k2, __ATOMIC_RELAXED, __HIP_MEMORY_SCOPE_AGENT);
                u64 xy = ((u64)__float_as_uint(y2) << 32) | __float_as_uint(x2);
                __hip_atomic_store(&r[1], xy, __ATOMIC_RELAXED, __HIP_MEMORY_SCOPE_AGENT);
                u64 meta = ((u64)((target << 17) | i2) << 32) | __float_as_uint(z2);
                // Release: orders w0/w1 before the tagged w2.
                __hip_atomic_store(&r[2], meta, __ATOMIC_RELEASE, __HIP_MEMORY_SCOPE_AGENT);
            }

            // Poll the 8 tag words lane-parallel (relaxed; no per-load inv).
            for (;;) {
                bool ok = true;
                if (lane < GPB) {
                    u64 w2 = __hip_atomic_load(&slot[lane * 3 + 2], __ATOMIC_RELAXED, __HIP_MEMORY_SCOPE_AGENT);
                    ok = (u32)(w2 >> 49) >= target;
                }
                if (__ballot(ok) == ~0ull) break;
                __builtin_amdgcn_s_sleep(1);
            }
            __builtin_amdgcn_fence(__ATOMIC_ACQUIRE, "agent");

            // Confirmed read: lanes 0..23 fetch word (lane%3) of group (lane/3)
            // in ONE round (no dependent loads), then shuffle-gather per group.
            u64 w = 0;
            if (lane < 3 * GPB)
                w = __hip_atomic_load(&slot[(lane / 3) * 3 + (lane % 3)], __ATOMIC_RELAXED, __HIP_MEMORY_SCOPE_AGENT);
            u64 k3w = __shfl(w, 3 * lane + 0, 64);
            u64 xyw = __shfl(w, 3 * lane + 1, 64);
            u64 mzw = __shfl(w, 3 * lane + 2, 64);
            u64   k3 = (lane < GPB) ? k3w : 0ull;
            u32   i3 = (lane < GPB) ? (u32)((mzw >> 32) & 0x1FFFFu) : 0xFFFFFFFFu;
            float x3 = __uint_as_float((u32)xyw);
            float y3 = __uint_as_float((u32)(xyw >> 32));
            float z3 = __uint_as_float((u32)mzw);
            red_step(k3, i3, x3, y3, z3, 4); red_step(k3, i3, x3, y3, z3, 2); red_step(k3, i3, x3, y3, z3, 1);
            if (lane == 0) { s_win = i3; s_cx = x3; s_cy = y3; s_cz = z3; }
        }
        __syncthreads();
        cur = (int)s_win; cx = s_cx; cy = s_cy; cz = s_cz;
    }
}

extern "C" void kernel_launch(void* const* d_in, const int* in_sizes, int n_in,
                              void* d_out, int out_size, void* d_ws, size_t ws_size,
                              hipStream_t stream)
{
    const float* coord = (const float*)d_in[0];
    const int*   seed  = (const int*)d_in[1];
    float* out = (float*)d_out;
    u64* rec = (u64*)d_ws;

    hipMemsetAsync(d_ws, 0, WS_BYTES, stream);
    fps_kernel<<<dim3(BATCHES * GPB), dim3(TPB), 0, stream>>>(coord, seed, out, rec);
}

// Round 6
// 6792.426 us; speedup vs baseline: 1.7060x; 1.0027x over previous
//
#include <hip/hip_runtime.h>
#include <stdint.h>

#define BATCHES 32
#define NPT     100000
#define NSAMP   1024
#define GPB     8          // blocks (groups) per batch -> 256 blocks = 1/CU
#define TPB     1024
#define PPB     12500      // points per block (8*12500 = 100000)
#define PPT     13         // k=0..11 full (12288), k=12 only tid<212
#define TAILT   212
#define NW      (TPB/64)   // 16 waves per block

typedef unsigned long long u64;
typedef unsigned int u32;

// Partial record per (slot, batch, group): 3 u64 = 24 B.
//   w0 = f64 distance bits (monotone for >= 0)
//   w1 = (y_bits<<32) | x_bits
//   w2 = (meta<<32)   | z_bits,  meta = (tag<<17) | idx   (tag=it+1 <= 1024)
#define WS_BYTES (2 * BATCHES * GPB * 3 * 8)   // 12 KB

__device__ __forceinline__ void red_step(u64& key, u32& idx, float& x, float& y, float& z, int off) {
    u64   ok = __shfl_xor(key, off, 64);
    u32   oi = __shfl_xor(idx, off, 64);
    float ox = __shfl_xor(x, off, 64);
    float oy = __shfl_xor(y, off, 64);
    float oz = __shfl_xor(z, off, 64);
    if (ok > key || (ok == key && oi < idx)) { key = ok; idx = oi; x = ox; y = oy; z = oz; }
}

// waves_per_eu(4,4): force the allocator to target exactly 4 waves/EU ->
// VGPR budget 128 (512/4). Persistent state (39 f32 + 13 f64 = 65 regs) plus
// temps fits -> NO scratch spills. 1024-thread blocks at 128 VGPR pin exactly
// 1 block/CU (16 waves). [launch_bounds(1024) or (1024,4) alone: allocator
// chose 64 VGPR / 8 waves-EU and spilled ~27 MB/iter to scratch - R2/R5 data]
__global__ void
__attribute__((amdgpu_flat_work_group_size(TPB, TPB), amdgpu_waves_per_eu(4, 4)))
fps_kernel(const float* __restrict__ coord,
           const int* __restrict__ seed_raw,
           float* __restrict__ out,
           u64* __restrict__ rec)
{
    const int tid  = threadIdx.x;
    const int lane = tid & 63;
    const int wid  = tid >> 6;
    // All 8 groups of a batch land on XCD b%8 under round-robin dispatch.
    const int b    = (int)blockIdx.x & 31;
    const int g    = (int)blockIdx.x >> 5;
    const int base = g * PPB;
    const float* cb = coord + (size_t)b * (NPT * 3);

    __shared__ u64   wkey[NW];
    __shared__ u32   widx[NW];
    __shared__ float wx[NW], wy[NW], wz[NW];
    __shared__ u32   s_win;
    __shared__ float s_cx, s_cy, s_cz;

    // Seed index (robust to int32 or int64 materialization of farthest_init).
    int odd = 0;
    #pragma unroll
    for (int i = 1; i < 32; i += 2) odd |= seed_raw[i];
    int cur = (odd == 0) ? seed_raw[2 * b] : seed_raw[b];

    float cx = cb[(size_t)cur * 3 + 0];
    float cy = cb[(size_t)cur * 3 + 1];
    float cz = cb[(size_t)cur * 3 + 2];

    // Coords (39 f32) AND running min-distance (13 f64) all in registers.
    float  px[PPT], py[PPT], pz[PPT];
    double d[PPT];
    #pragma unroll
    for (int k = 0; k < PPT; ++k) {
        bool v = (k < 12) || (tid < TAILT);
        int gi = base + (v ? (k * TPB + tid) : 0);
        px[k] = v ? cb[(size_t)gi * 3 + 0] : 0.f;
        py[k] = v ? cb[(size_t)gi * 3 + 1] : 0.f;
        pz[k] = v ? cb[(size_t)gi * 3 + 2] : 0.f;
        d[k]  = v ? 1.0e10 : 0.0;   // fake points can never win argmax
    }

    float* cent_out = out;                       // (B, 1024) as float
    float* samp_out = out + BATCHES * NSAMP;     // (B, 1024, 3)

    for (int it = 0; it < NSAMP; ++it) {
        // Outputs written by the otherwise-idle wave 1 (off the sync path).
        if (g == 0 && wid == 1 && lane == 0) {
            cent_out[b * NSAMP + it] = (float)cur;
            size_t so = ((size_t)b * NSAMP + it) * 3;
            samp_out[so + 0] = cx; samp_out[so + 1] = cy; samp_out[so + 2] = cz;
        }

        const double cxd = (double)cx, cyd = (double)cy, czd = (double)cz;

        // f64 update + per-thread argmax. Explicit _rn ops forbid FMA
        // contraction; sum order ((dx^2+dy^2)+dz^2) matches np.sum(axis=-1).
        double bd = -1.0; u32 bi = 0; float bx = 0.f, by = 0.f, bz = 0.f;
        #pragma unroll
        for (int k = 0; k < PPT; ++k) {
            if (k == 12 && tid >= TAILT) break;
            double dx = __dsub_rn((double)px[k], cxd);
            double dy = __dsub_rn((double)py[k], cyd);
            double dz = __dsub_rn((double)pz[k], czd);
            double d2 = __dadd_rn(__dadd_rn(__dmul_rn(dx, dx), __dmul_rn(dy, dy)),
                                  __dmul_rn(dz, dz));
            double nd = fmin(d[k], d2);
            d[k] = nd;
            bool gt = nd > bd;       // strict > keeps smallest k (== smallest idx)
            bd = gt ? nd : bd;
            bi = gt ? (u32)(base + k * TPB + tid) : bi;
            bx = gt ? px[k] : bx;
            by = gt ? py[k] : by;
            bz = gt ? pz[k] : bz;
        }
        u64 key = (u64)__double_as_longlong(bd);   // bd >= 0 -> monotone bits

        // Wave butterfly reduction.
        red_step(key, bi, bx, by, bz, 32); red_step(key, bi, bx, by, bz, 16);
        red_step(key, bi, bx, by, bz, 8);  red_step(key, bi, bx, by, bz, 4);
        red_step(key, bi, bx, by, bz, 2);  red_step(key, bi, bx, by, bz, 1);
        if (lane == 0) { wkey[wid] = key; widx[wid] = bi; wx[wid] = bx; wy[wid] = by; wz[wid] = bz; }
        __syncthreads();

        if (wid == 0) {
            // Block reduce over 16 wave partials (lanes 0..15).
            u64   k2 = (lane < NW) ? wkey[lane] : 0ull;
            u32   i2 = (lane < NW) ? widx[lane] : 0xFFFFFFFFu;
            float x2 = (lane < NW) ? wx[lane] : 0.f;
            float y2 = (lane < NW) ? wy[lane] : 0.f;
            float z2 = (lane < NW) ? wz[lane] : 0.f;
            red_step(k2, i2, x2, y2, z2, 8); red_step(k2, i2, x2, y2, z2, 4);
            red_step(k2, i2, x2, y2, z2, 2); red_step(k2, i2, x2, y2, z2, 1);

            const int s = it & 1;                       // parity double-buffer
            u64* slot = rec + ((size_t)(s * BATCHES + b) * GPB) * 3;
            const u32 target = (u32)(it + 1);
            if (lane == 0) {
                u64* r = slot + g * 3;
                __hip_atomic_store(&r[0], k2, __ATOMIC_RELAXED, __HIP_MEMORY_SCOPE_AGENT);
                u64 xy = ((u64)__float_as_uint(y2) << 32) | __float_as_uint(x2);
                __hip_atomic_store(&r[1], xy, __ATOMIC_RELAXED, __HIP_MEMORY_SCOPE_AGENT);
                u64 meta = ((u64)((target << 17) | i2) << 32) | __float_as_uint(z2);
                // Release: orders w0/w1 before the tagged w2.
                __hip_atomic_store(&r[2], meta, __ATOMIC_RELEASE, __HIP_MEMORY_SCOPE_AGENT);
            }

            // Poll the 8 tag words lane-parallel (relaxed; no per-load inv).
            for (;;) {
                bool ok = true;
                if (lane < GPB) {
                    u64 w2 = __hip_atomic_load(&slot[lane * 3 + 2], __ATOMIC_RELAXED, __HIP_MEMORY_SCOPE_AGENT);
                    ok = (u32)(w2 >> 49) >= target;
                }
                if (__ballot(ok) == ~0ull) break;
                __builtin_amdgcn_s_sleep(1);
            }
            __builtin_amdgcn_fence(__ATOMIC_ACQUIRE, "agent");

            // Confirmed read: lanes 0..23 fetch word (lane%3) of group (lane/3)
            // in ONE round (no dependent loads), then shuffle-gather per group.
            u64 w = 0;
            if (lane < 3 * GPB)
                w = __hip_atomic_load(&slot[(lane / 3) * 3 + (lane % 3)], __ATOMIC_RELAXED, __HIP_MEMORY_SCOPE_AGENT);
            u64 k3w = __shfl(w, 3 * lane + 0, 64);
            u64 xyw = __shfl(w, 3 * lane + 1, 64);
            u64 mzw = __shfl(w, 3 * lane + 2, 64);
            u64   k3 = (lane < GPB) ? k3w : 0ull;
            u32   i3 = (lane < GPB) ? (u32)((mzw >> 32) & 0x1FFFFu) : 0xFFFFFFFFu;
            float x3 = __uint_as_float((u32)xyw);
            float y3 = __uint_as_float((u32)(xyw >> 32));
            float z3 = __uint_as_float((u32)mzw);
            red_step(k3, i3, x3, y3, z3, 4); red_step(k3, i3, x3, y3, z3, 2); red_step(k3, i3, x3, y3, z3, 1);
            if (lane == 0) { s_win = i3; s_cx = x3; s_cy = y3; s_cz = z3; }
        }
        __syncthreads();
        cur = (int)s_win; cx = s_cx; cy = s_cy; cz = s_cz;
    }
}

extern "C" void kernel_launch(void* const* d_in, const int* in_sizes, int n_in,
                              void* d_out, int out_size, void* d_ws, size_t ws_size,
                              hipStream_t stream)
{
    const float* coord = (const float*)d_in[0];
    const int*   seed  = (const int*)d_in[1];
    float* out = (float*)d_out;
    u64* rec = (u64*)d_ws;

    hipMemsetAsync(d_ws, 0, WS_BYTES, stream);
    fps_kernel<<<dim3(BATCHES * GPB), dim3(TPB), 0, stream>>>(coord, seed, out, rec);
}

// Round 7
// 4659.754 us; speedup vs baseline: 2.4868x; 1.4577x over previous
//
#include <hip/hip_runtime.h>
#include <stdint.h>

#define BATCHES 32
#define NPT     100000
#define NSAMP   1024
#define GPB     8          // blocks (groups) per batch -> 256 blocks = 1/CU
#define TPB     1024
#define PPB     12500      // points per block (8*12500 = 100000)
#define PPT     13         // k=0..11 full (12288), k=12 only tid<212
#define TAILT   212
#define NW      (TPB/64)   // 16 waves per block

typedef unsigned long long u64;
typedef unsigned int u32;

// Record per (parity, batch, group): 4 u64 (32B, w3 unused pad).
// Each word carries tag2 in bits [63:62]; payload below. A poller that last
// consumed this slot saw tag(it-1); coherence makes later reads >= that
// version, so the only observable tags are tag(it-1) and tag(it+1), which
// tag2 = (((it+1)>>1)+1)&3 distinguishes (consecutive same-parity iters
// differ by 1 mod 4; +1 offset makes the memset-0 state invalid).
//   w0 = tag2 | key[61:0]
//   w1 = tag2 | key[63:62]<<60 | x<<28 | y>>4
//   w2 = tag2 | (y&0xF)<<58   | z<<26 | idx<<9
#define WS_BYTES (2 * BATCHES * GPB * 4 * 8)   // 16 KB

__device__ __forceinline__ void red_step(u64& key, u32& idx, float& x, float& y, float& z, int off) {
    u64   ok = __shfl_xor(key, off, 64);
    u32   oi = __shfl_xor(idx, off, 64);
    float ox = __shfl_xor(x, off, 64);
    float oy = __shfl_xor(y, off, 64);
    float oz = __shfl_xor(z, off, 64);
    if (ok > key || (ok == key && oi < idx)) { key = ok; idx = oi; x = ox; y = oy; z = oz; }
}

__global__ void
__attribute__((amdgpu_flat_work_group_size(TPB, TPB), amdgpu_waves_per_eu(4, 4)))
fps_kernel(const float* __restrict__ coord,
           const int* __restrict__ seed_raw,
           float* __restrict__ out,
           u64* __restrict__ rec)
{
    const int tid  = threadIdx.x;
    const int lane = tid & 63;
    const int wid  = tid >> 6;
    // All 8 groups of a batch land on XCD b%8 under round-robin dispatch.
    const int b    = (int)blockIdx.x & 31;
    const int g    = (int)blockIdx.x >> 5;
    const int base = g * PPB;
    const float* cb = coord + (size_t)b * (NPT * 3);

    __shared__ u64   wkey[NW];
    __shared__ u32   widx[NW];
    __shared__ float wx[NW], wy[NW], wz[NW];
    __shared__ u32   s_win;
    __shared__ float s_cx, s_cy, s_cz;

    // Seed index (robust to int32 or int64 materialization of farthest_init).
    int odd = 0;
    #pragma unroll
    for (int i = 1; i < 32; i += 2) odd |= seed_raw[i];
    int cur = (odd == 0) ? seed_raw[2 * b] : seed_raw[b];

    float cx = cb[(size_t)cur * 3 + 0];
    float cy = cb[(size_t)cur * 3 + 1];
    float cz = cb[(size_t)cur * 3 + 2];

    // Coords (39 f32) AND running min-distance (13 f64) in registers
    // (overflow spills to AGPRs on the unified file, not scratch - R6 data).
    float  px[PPT], py[PPT], pz[PPT];
    double d[PPT];
    #pragma unroll
    for (int k = 0; k < PPT; ++k) {
        bool v = (k < 12) || (tid < TAILT);
        int gi = base + (v ? (k * TPB + tid) : 0);
        px[k] = v ? cb[(size_t)gi * 3 + 0] : 0.f;
        py[k] = v ? cb[(size_t)gi * 3 + 1] : 0.f;
        pz[k] = v ? cb[(size_t)gi * 3 + 2] : 0.f;
        d[k]  = v ? 1.0e10 : 0.0;   // fake points can never win argmax
    }

    float* cent_out = out;                       // (B, 1024) as float
    float* samp_out = out + BATCHES * NSAMP;     // (B, 1024, 3)

    for (int it = 0; it < NSAMP; ++it) {
        // Outputs written by the otherwise-idle wave 1 (off the sync path).
        if (g == 0 && wid == 1 && lane == 0) {
            cent_out[b * NSAMP + it] = (float)cur;
            size_t so = ((size_t)b * NSAMP + it) * 3;
            samp_out[so + 0] = cx; samp_out[so + 1] = cy; samp_out[so + 2] = cz;
        }

        const double cxd = (double)cx, cyd = (double)cy, czd = (double)cz;

        // f64 update + per-thread argmax. Explicit _rn ops forbid FMA
        // contraction; sum order ((dx^2+dy^2)+dz^2) matches np.sum(axis=-1).
        double bd = -1.0; u32 bi = 0; float bx = 0.f, by = 0.f, bz = 0.f;
        #pragma unroll
        for (int k = 0; k < PPT; ++k) {
            if (k == 12 && tid >= TAILT) break;
            double dx = __dsub_rn((double)px[k], cxd);
            double dy = __dsub_rn((double)py[k], cyd);
            double dz = __dsub_rn((double)pz[k], czd);
            double d2 = __dadd_rn(__dadd_rn(__dmul_rn(dx, dx), __dmul_rn(dy, dy)),
                                  __dmul_rn(dz, dz));
            double nd = fmin(d[k], d2);
            d[k] = nd;
            bool gt = nd > bd;       // strict > keeps smallest k (== smallest idx)
            bd = gt ? nd : bd;
            bi = gt ? (u32)(base + k * TPB + tid) : bi;
            bx = gt ? px[k] : bx;
            by = gt ? py[k] : by;
            bz = gt ? pz[k] : bz;
        }
        u64 key = (u64)__double_as_longlong(bd);   // bd >= 0 -> monotone bits

        // Wave butterfly reduction.
        red_step(key, bi, bx, by, bz, 32); red_step(key, bi, bx, by, bz, 16);
        red_step(key, bi, bx, by, bz, 8);  red_step(key, bi, bx, by, bz, 4);
        red_step(key, bi, bx, by, bz, 2);  red_step(key, bi, bx, by, bz, 1);
        if (lane == 0) { wkey[wid] = key; widx[wid] = bi; wx[wid] = bx; wy[wid] = by; wz[wid] = bz; }
        __syncthreads();

        if (wid == 0) {
            // Block reduce over 16 wave partials (lanes 0..15).
            u64   k2 = (lane < NW) ? wkey[lane] : 0ull;
            u32   i2 = (lane < NW) ? widx[lane] : 0xFFFFFFFFu;
            float x2 = (lane < NW) ? wx[lane] : 0.f;
            float y2 = (lane < NW) ? wy[lane] : 0.f;
            float z2 = (lane < NW) ? wz[lane] : 0.f;
            red_step(k2, i2, x2, y2, z2, 8); red_step(k2, i2, x2, y2, z2, 4);
            red_step(k2, i2, x2, y2, z2, 2); red_step(k2, i2, x2, y2, z2, 1);

            const int s = it & 1;                       // parity double-buffer
            u64* slot = rec + ((size_t)(s * BATCHES + b) * GPB) * 4;
            const u64 t2 = (u64)((((it + 1) >> 1) + 1) & 3);

            if (lane == 0) {
                u32 xb = __float_as_uint(x2), yb = __float_as_uint(y2), zb = __float_as_uint(z2);
                u64 w0 = (t2 << 62) | (k2 & 0x3FFFFFFFFFFFFFFFull);
                u64 w1 = (t2 << 62) | ((k2 >> 62) << 60) | ((u64)xb << 28) | (u64)(yb >> 4);
                u64 w2 = (t2 << 62) | ((u64)(yb & 0xFu) << 58) | ((u64)zb << 26) | ((u64)i2 << 9);
                u64* r = slot + g * 4;
                // Three relaxed stores: no release -> no vmcnt drain; all three
                // fly concurrently (self-validating words, order irrelevant).
                __hip_atomic_store(&r[0], w0, __ATOMIC_RELAXED, __HIP_MEMORY_SCOPE_AGENT);
                __hip_atomic_store(&r[1], w1, __ATOMIC_RELAXED, __HIP_MEMORY_SCOPE_AGENT);
                __hip_atomic_store(&r[2], w2, __ATOMIC_RELAXED, __HIP_MEMORY_SCOPE_AGENT);
            }

            // Poll: lanes 0..7 read group lane's 3 words (independent loads ->
            // one RTT per round). Tags valid => payload IS the data: no fence,
            // no confirm read.
            u64 w0 = 0, w1 = 0, w2 = 0;
            for (;;) {
                bool ok = true;
                if (lane < GPB) {
                    u64* r = slot + lane * 4;
                    w0 = __hip_atomic_load(&r[0], __ATOMIC_RELAXED, __HIP_MEMORY_SCOPE_AGENT);
                    w1 = __hip_atomic_load(&r[1], __ATOMIC_RELAXED, __HIP_MEMORY_SCOPE_AGENT);
                    w2 = __hip_atomic_load(&r[2], __ATOMIC_RELAXED, __HIP_MEMORY_SCOPE_AGENT);
                    ok = ((w0 >> 62) == t2) & ((w1 >> 62) == t2) & ((w2 >> 62) == t2);
                }
                if (__ballot(ok) == ~0ull) break;
                __builtin_amdgcn_s_sleep(1);
            }

            // Unpack + final butterfly over 8 group records.
            u64   k3 = 0ull; u32 i3 = 0xFFFFFFFFu;
            float x3 = 0.f, y3 = 0.f, z3 = 0.f;
            if (lane < GPB) {
                k3 = (w0 & 0x3FFFFFFFFFFFFFFFull) | (((w1 >> 60) & 3ull) << 62);
                u32 xb = (u32)(w1 >> 28);
                u32 yb = (u32)(((w1 & 0xFFFFFFFull) << 4) | ((w2 >> 58) & 0xFull));
                u32 zb = (u32)(w2 >> 26);
                i3 = (u32)((w2 >> 9) & 0x1FFFFu);
                x3 = __uint_as_float(xb);
                y3 = __uint_as_float(yb);
                z3 = __uint_as_float(zb);
            }
            red_step(k3, i3, x3, y3, z3, 4); red_step(k3, i3, x3, y3, z3, 2); red_step(k3, i3, x3, y3, z3, 1);
            if (lane == 0) { s_win = i3; s_cx = x3; s_cy = y3; s_cz = z3; }
        }
        __syncthreads();
        cur = (int)s_win; cx = s_cx; cy = s_cy; cz = s_cz;
    }
}

extern "C" void kernel_launch(void* const* d_in, const int* in_sizes, int n_in,
                              void* d_out, int out_size, void* d_ws, size_t ws_size,
                              hipStream_t stream)
{
    const float* coord = (const float*)d_in[0];
    const int*   seed  = (const int*)d_in[1];
    float* out = (float*)d_out;
    u64* rec = (u64*)d_ws;

    hipMemsetAsync(d_ws, 0, WS_BYTES, stream);
    fps_kernel<<<dim3(BATCHES * GPB), dim3(TPB), 0, stream>>>(coord, seed, out, rec);
}